// Round 1
// baseline (269.235 us; speedup 1.0000x reference)
//
#include <hip/hip_runtime.h>
#include <hip/hip_bf16.h>
#include <stdint.h>

#define B_DIM 4096
#define IN_DIM 1024
#define H_DIM 1024
#define K_DIM 2048   // IN + H
#define N_DIM 4096   // 4*H
#define BH (B_DIM * H_DIM)

// GEMM tile (m97 structure: 128x128 tile, BK=64, 4 waves in 2x2)
#define BM 128
#define BN 128
#define BK 64

typedef __bf16 bf16x8 __attribute__((ext_vector_type(8)));
typedef float  f32x4  __attribute__((ext_vector_type(4)));

// ---------------------------------------------------------------- helpers
__device__ __forceinline__ unsigned short f2b(float f) {
  // round-to-nearest-even fp32 -> bf16 (inputs are finite)
  uint32_t u = __builtin_bit_cast(uint32_t, f);
  u += 0x7fffu + ((u >> 16) & 1u);
  return (unsigned short)(u >> 16);
}

__device__ __forceinline__ void load_lds16(const void* g, void* l) {
  __builtin_amdgcn_global_load_lds(
      (const __attribute__((address_space(1))) uint32_t*)g,
      (__attribute__((address_space(3))) uint32_t*)l, 16, 0, 0);
}

__device__ __forceinline__ float sigmoidf_(float x) {
  return 1.0f / (1.0f + __expf(-x));
}
__device__ __forceinline__ float tanhf_(float x) {
  // tanh via exp; |arg| stays < ~20 for this problem, no overflow risk at 2x
  float e = __expf(-2.0f * x);
  return (1.0f - e) / (1.0f + e);
}

// ---------------------------------------------------------------- pack A = [x | h_prev] -> bf16 [4096][2048]
__global__ void pack_a(const float* __restrict__ x, const float* __restrict__ h,
                       unsigned short* __restrict__ A) {
  int t = blockIdx.x * 256 + threadIdx.x;   // 2M threads, 4 elems each
  int e = t * 4;                            // element index in [0, 8M)
  int b = e >> 11;                          // row (batch)
  int k = e & 2047;                         // col in concat-K
  const float* src = (k < IN_DIM) ? (x + (size_t)b * IN_DIM + k)
                                  : (h + (size_t)b * H_DIM + (k - IN_DIM));
  f32x4 v = *(const f32x4*)src;
  ushort4 o;
  o.x = f2b(v[0]); o.y = f2b(v[1]); o.z = f2b(v[2]); o.w = f2b(v[3]);
  *(ushort4*)(A + (size_t)b * K_DIM + k) = o;
}

// ---------------------------------------------------------------- pack W -> bf16 [4096][2048]
// row n: gate = n>>10 (i,f,g,o), j = n&1023; cols [0,1024)=W_x[j], [1024,2048)=W_h[j]
__global__ void pack_w(const float* __restrict__ Wii, const float* __restrict__ Wif,
                       const float* __restrict__ Wig, const float* __restrict__ Wio,
                       const float* __restrict__ Whi, const float* __restrict__ Whf,
                       const float* __restrict__ Whg, const float* __restrict__ Who,
                       unsigned short* __restrict__ W) {
  int t = blockIdx.x * 256 + threadIdx.x;   // 2M threads, 4 elems each
  int e = t * 4;
  int n = e >> 11;
  int k = e & 2047;
  int gate = n >> 10;   // uniform per block (block covers 1024 contiguous elems)
  int j = n & 1023;
  const float* Wx = (gate == 0) ? Wii : (gate == 1) ? Wif : (gate == 2) ? Wig : Wio;
  const float* Wh = (gate == 0) ? Whi : (gate == 1) ? Whf : (gate == 2) ? Whg : Who;
  const float* src = (k < IN_DIM) ? (Wx + (size_t)j * IN_DIM + k)
                                  : (Wh + (size_t)j * H_DIM + (k - IN_DIM));
  f32x4 v = *(const f32x4*)src;
  ushort4 o;
  o.x = f2b(v[0]); o.y = f2b(v[1]); o.z = f2b(v[2]); o.w = f2b(v[3]);
  *(ushort4*)(W + (size_t)n * K_DIM + k) = o;
}

// ---------------------------------------------------------------- GEMM: gates[b][n] = sum_k A[b][k]*W[n][k]
__global__ __launch_bounds__(256) void gemm_gates(
    const unsigned short* __restrict__ A,   // bf16 [4096][2048]
    const unsigned short* __restrict__ W,   // bf16 [4096][2048]
    float* __restrict__ C) {                // fp32 [4096][4096]
  __shared__ unsigned short Als[BM * BK];   // 16 KB
  __shared__ unsigned short Bls[BN * BK];   // 16 KB

  const int tid  = threadIdx.x;
  const int lane = tid & 63;
  const int wid  = tid >> 6;
  const int wr   = wid >> 1;    // wave row (0..1)
  const int wc   = wid & 1;     // wave col (0..1)
  const int bx   = blockIdx.x;  // N tile
  const int by   = blockIdx.y;  // M tile

  f32x4 acc[4][4];
#pragma unroll
  for (int m = 0; m < 4; ++m)
#pragma unroll
    for (int n = 0; n < 4; ++n) acc[m][n] = (f32x4){0.f, 0.f, 0.f, 0.f};

  const unsigned short* Ag = A + (size_t)by * BM * K_DIM;
  const unsigned short* Wg = W + (size_t)bx * BN * K_DIM;

  const int lrow = lane & 15;
  const int lk   = (lane >> 4) * 8;

  for (int k0 = 0; k0 < K_DIM; k0 += BK) {
    __syncthreads();  // previous iteration's LDS reads done before overwrite
#pragma unroll
    for (int r = 0; r < 4; ++r) {
      int c = tid + 256 * r;          // chunk id: 1024 chunks of 16B
      int row = c >> 3, c8 = c & 7;   // 8 chunks per 64-elem row
      load_lds16(Ag + (size_t)row * K_DIM + k0 + c8 * 8, &Als[c * 8]);
    }
#pragma unroll
    for (int r = 0; r < 4; ++r) {
      int c = tid + 256 * r;
      int row = c >> 3, c8 = c & 7;
      load_lds16(Wg + (size_t)row * K_DIM + k0 + c8 * 8, &Bls[c * 8]);
    }
    __syncthreads();  // drains vmcnt before use (compiler-inserted)

#pragma unroll
    for (int kk = 0; kk < 2; ++kk) {
      bf16x8 af[4], bfr[4];
#pragma unroll
      for (int m = 0; m < 4; ++m)
        af[m] = *(const bf16x8*)&Als[(wr * 64 + m * 16 + lrow) * BK + kk * 32 + lk];
#pragma unroll
      for (int n = 0; n < 4; ++n)
        bfr[n] = *(const bf16x8*)&Bls[(wc * 64 + n * 16 + lrow) * BK + kk * 32 + lk];
#pragma unroll
      for (int m = 0; m < 4; ++m)
#pragma unroll
        for (int n = 0; n < 4; ++n)
          acc[m][n] = __builtin_amdgcn_mfma_f32_16x16x32_bf16(af[m], bfr[n], acc[m][n], 0, 0, 0);
    }
  }

  // C/D layout: col = lane&15, row = (lane>>4)*4 + reg
  const int r0 = by * BM + wr * 64;
  const int c0 = bx * BN + wc * 64;
#pragma unroll
  for (int m = 0; m < 4; ++m) {
#pragma unroll
    for (int n = 0; n < 4; ++n) {
      int row = r0 + m * 16 + (lane >> 4) * 4;
      int col = c0 + n * 16 + (lane & 15);
#pragma unroll
      for (int r = 0; r < 4; ++r)
        C[(size_t)(row + r) * N_DIM + col] = acc[m][n][r];
    }
  }
}

// ---------------------------------------------------------------- epilogue
__global__ void lstm_epilogue(const float* __restrict__ gates,   // [4096][4096]
                              const float* __restrict__ c_prev,  // [4096][1024]
                              const float* __restrict__ b_i, const float* __restrict__ b_f,
                              const float* __restrict__ b_g, const float* __restrict__ b_o,
                              float* __restrict__ out) {         // [3*BH]
  int t = blockIdx.x * 256 + threadIdx.x;  // 1M threads, 4 elems each
  int e = t * 4;                           // element in [0, 4M)
  int b = e >> 10;
  int j = e & 1023;
  size_t rowbase = (size_t)b * N_DIM;
  f32x4 ig = *(const f32x4*)&gates[rowbase + j];
  f32x4 fg = *(const f32x4*)&gates[rowbase + 1024 + j];
  f32x4 gg = *(const f32x4*)&gates[rowbase + 2048 + j];
  f32x4 og = *(const f32x4*)&gates[rowbase + 3072 + j];
  f32x4 bi = *(const f32x4*)&b_i[j];
  f32x4 bf = *(const f32x4*)&b_f[j];
  f32x4 bg = *(const f32x4*)&b_g[j];
  f32x4 bo = *(const f32x4*)&b_o[j];
  f32x4 cp = *(const f32x4*)&c_prev[e];

  f32x4 h4, c4;
#pragma unroll
  for (int r = 0; r < 4; ++r) {
    float i_t = sigmoidf_(ig[r] + bi[r]);
    float f_t = sigmoidf_(fg[r] + bf[r]);
    float g_t = tanhf_(gg[r] + bg[r]);
    float o_t = sigmoidf_(og[r] + bo[r]);
    float c_t = f_t * cp[r] + i_t * g_t;
    c4[r] = c_t;
    h4[r] = o_t * tanhf_(c_t);
  }
  *(f32x4*)&out[e]          = h4;  // h_t (output 0)
  *(f32x4*)&out[BH + e]     = h4;  // h_t (output 1)
  *(f32x4*)&out[2 * BH + e] = c4;  // c_t (output 2)
}

// ---------------------------------------------------------------- launcher
extern "C" void kernel_launch(void* const* d_in, const int* in_sizes, int n_in,
                              void* d_out, int out_size, void* d_ws, size_t ws_size,
                              hipStream_t stream) {
  const float* x   = (const float*)d_in[0];
  const float* hp  = (const float*)d_in[1];
  const float* cp  = (const float*)d_in[2];
  const float* Wii = (const float*)d_in[3];
  const float* Whi = (const float*)d_in[4];
  const float* bi  = (const float*)d_in[5];
  const float* Wif = (const float*)d_in[6];
  const float* Whf = (const float*)d_in[7];
  const float* bf  = (const float*)d_in[8];
  const float* Wig = (const float*)d_in[9];
  const float* Whg = (const float*)d_in[10];
  const float* bg  = (const float*)d_in[11];
  const float* Wio = (const float*)d_in[12];
  const float* Who = (const float*)d_in[13];
  const float* bo  = (const float*)d_in[14];

  unsigned short* Abf   = (unsigned short*)d_ws;                               // 16 MiB
  unsigned short* Wbf   = (unsigned short*)((char*)d_ws + (16u << 20));        // 16 MiB
  float*          gates = (float*)((char*)d_ws + (32u << 20));                 // 64 MiB
  float*          out   = (float*)d_out;

  // pack A: 8M elems / 4 per thread = 2M threads
  pack_a<<<8192, 256, 0, stream>>>(x, hp, Abf);
  // pack W: 8M elems / 4 per thread
  pack_w<<<8192, 256, 0, stream>>>(Wii, Wif, Wig, Wio, Whi, Whf, Whg, Who, Wbf);
  // GEMM: 32x32 tiles of 128x128
  gemm_gates<<<dim3(N_DIM / BN, B_DIM / BM), 256, 0, stream>>>(Abf, Wbf, gates);
  // epilogue: 4M elems / 4 per thread
  lstm_epilogue<<<4096, 256, 0, stream>>>(gates, cp, bi, bf, bg, bo, out);
}

// Round 2
// 241.501 us; speedup vs baseline: 1.1148x; 1.1148x over previous
//
#include <hip/hip_runtime.h>
#include <hip/hip_bf16.h>
#include <stdint.h>

#define B_DIM 4096
#define IN_DIM 1024
#define H_DIM 1024
#define K_DIM 2048   // IN + H
#define N_DIM 4096   // 4*H
#define BH (B_DIM * H_DIM)
#define NT 32        // K tiles of 64

typedef __bf16 bf16x8 __attribute__((ext_vector_type(8)));
typedef float  f32x4  __attribute__((ext_vector_type(4)));

// ---------------------------------------------------------------- helpers
__device__ __forceinline__ unsigned short f2b(float f) {
  uint32_t u = __builtin_bit_cast(uint32_t, f);
  u += 0x7fffu + ((u >> 16) & 1u);
  return (unsigned short)(u >> 16);
}

__device__ __forceinline__ void load_lds16(const void* g, void* l) {
  __builtin_amdgcn_global_load_lds(
      (const __attribute__((address_space(1))) uint32_t*)g,
      (__attribute__((address_space(3))) uint32_t*)l, 16, 0, 0);
}

__device__ __forceinline__ void bar() {
  asm volatile("" ::: "memory");
  __builtin_amdgcn_s_barrier();
  asm volatile("" ::: "memory");
}

__device__ __forceinline__ float sigmoidf_(float x) {
  return 1.0f / (1.0f + __expf(-x));
}
__device__ __forceinline__ float tanhf_(float x) {
  float e = __expf(-2.0f * x);
  return (1.0f - e) / (1.0f + e);
}

// ---------------------------------------------------------------- pack A = [x | h_prev] -> bf16 [4096][2048]
__global__ void pack_a(const float* __restrict__ x, const float* __restrict__ h,
                       unsigned short* __restrict__ A) {
  int t = blockIdx.x * 256 + threadIdx.x;
  int e = t * 4;
  int b = e >> 11;
  int k = e & 2047;
  const float* src = (k < IN_DIM) ? (x + (size_t)b * IN_DIM + k)
                                  : (h + (size_t)b * H_DIM + (k - IN_DIM));
  f32x4 v = *(const f32x4*)src;
  ushort4 o;
  o.x = f2b(v[0]); o.y = f2b(v[1]); o.z = f2b(v[2]); o.w = f2b(v[3]);
  *(ushort4*)(A + (size_t)b * K_DIM + k) = o;
}

// ---------------------------------------------------------------- pack W -> bf16 [4096][2048]
__global__ void pack_w(const float* __restrict__ Wii, const float* __restrict__ Wif,
                       const float* __restrict__ Wig, const float* __restrict__ Wio,
                       const float* __restrict__ Whi, const float* __restrict__ Whf,
                       const float* __restrict__ Whg, const float* __restrict__ Who,
                       unsigned short* __restrict__ W) {
  int t = blockIdx.x * 256 + threadIdx.x;
  int e = t * 4;
  int n = e >> 11;
  int k = e & 2047;
  int gate = n >> 10;
  int j = n & 1023;
  const float* Wx = (gate == 0) ? Wii : (gate == 1) ? Wif : (gate == 2) ? Wig : Wio;
  const float* Wh = (gate == 0) ? Whi : (gate == 1) ? Whf : (gate == 2) ? Whg : Who;
  const float* src = (k < IN_DIM) ? (Wx + (size_t)j * IN_DIM + k)
                                  : (Wh + (size_t)j * H_DIM + (k - IN_DIM));
  f32x4 v = *(const f32x4*)src;
  ushort4 o;
  o.x = f2b(v[0]); o.y = f2b(v[1]); o.z = f2b(v[2]); o.w = f2b(v[3]);
  *(ushort4*)(W + (size_t)n * K_DIM + k) = o;
}

// ---------------------------------------------------------------- GEMM (256x256 tile, 8-phase, counted vmcnt)
// gates[b][n] = sum_k A[b][k] * W[n][k]
//
// LDS: [slot][A=0/B=1][half][128 rows x 64 k] bf16, 128 KiB total.
// Stage: linear LDS dest (global_load_lds), inverse-swizzled global source.
// Read: ds_read_b128 with byte ^= (row&7)<<4 swizzle (T2) -> ~2-way conflicts.
// Schedule per tile t (slot s=t&1), quadrants (mq,nq)=(0,0),(0,1),(1,0),(1,1):
//   ph1 reads A-h0,B-h0; stages A-h1(t+1)->s^1   (A-h1(s^1) free since t-1.ph4)
//   ph2 reads A-h0,B-h1; stages B-h1(t+1)->s^1   (free since t-1.ph4)
//   ph3 reads A-h1,B-h0; stages A-h0(t+2)->s     (A-h0(s) free after ph2)
//   ph4 reads A-h1,B-h1; stages B-h0(t+2)->s     (B-h0(s) free after ph3)
//   ph4 end: s_waitcnt vmcnt(4)  -> all of tile t+1 landed; only t+2's
//            A-h0/B-h0 (newest 4 loads) may remain in flight.

#define STAGE(ldsbase, gbase, kelem) do {                                        \
  const unsigned short* g0_ = (gbase) + (size_t)srow0 * K_DIM + (kelem) + schunk * 8; \
  load_lds16(g0_, (ldsbase) + tid * 8);                                          \
  load_lds16(g0_ + (size_t)64 * K_DIM, (ldsbase) + 4096 + tid * 8);              \
} while (0)

#define PHASE(SLOT, MQ, NQ, STAGE_STMT, VM_WAIT) do {                            \
  const unsigned short* As_ = &lds[SLOT][0][MQ][0];                              \
  const unsigned short* Bs_ = &lds[SLOT][1][NQ][0];                              \
  bf16x8 af[4][2], bq[2][2];                                                     \
  _Pragma("unroll")                                                              \
  for (int m = 0; m < 4; ++m) {                                                  \
    int ro = (wr * 64 + m * 16 + lrow) * 64;                                     \
    af[m][0] = *(const bf16x8*)(As_ + ro + ks0);                                 \
    af[m][1] = *(const bf16x8*)(As_ + ro + ks1);                                 \
  }                                                                              \
  _Pragma("unroll")                                                              \
  for (int n = 0; n < 2; ++n) {                                                  \
    int ro = (wc * 32 + n * 16 + lrow) * 64;                                     \
    bq[n][0] = *(const bf16x8*)(Bs_ + ro + ks0);                                 \
    bq[n][1] = *(const bf16x8*)(Bs_ + ro + ks1);                                 \
  }                                                                              \
  STAGE_STMT;                                                                    \
  bar();                                                                         \
  asm volatile("s_waitcnt lgkmcnt(0)" ::: "memory");                             \
  __builtin_amdgcn_sched_barrier(0);                                             \
  __builtin_amdgcn_s_setprio(1);                                                 \
  _Pragma("unroll")                                                              \
  for (int m = 0; m < 4; ++m)                                                    \
    _Pragma("unroll")                                                            \
    for (int n = 0; n < 2; ++n) {                                                \
      acc[MQ][NQ][m][n] = __builtin_amdgcn_mfma_f32_16x16x32_bf16(               \
          af[m][0], bq[n][0], acc[MQ][NQ][m][n], 0, 0, 0);                       \
      acc[MQ][NQ][m][n] = __builtin_amdgcn_mfma_f32_16x16x32_bf16(               \
          af[m][1], bq[n][1], acc[MQ][NQ][m][n], 0, 0, 0);                       \
    }                                                                            \
  __builtin_amdgcn_s_setprio(0);                                                 \
  __builtin_amdgcn_sched_barrier(0);                                             \
  VM_WAIT;                                                                       \
  bar();                                                                         \
} while (0)

__global__ __launch_bounds__(512, 2) void gemm_gates(
    const unsigned short* __restrict__ A,   // bf16 [4096][2048]
    const unsigned short* __restrict__ W,   // bf16 [4096][2048]
    float* __restrict__ C) {                // fp32 [4096][4096]
  __shared__ unsigned short lds[2][2][2][128 * 64];   // 128 KiB

  const int tid  = threadIdx.x;
  const int lane = tid & 63;
  const int wid  = tid >> 6;
  const int wr   = wid >> 2;     // 0..1
  const int wc   = wid & 3;      // 0..3
  const int lrow = lane & 15;

  // T1: bijective XCD swizzle (256 blocks, 8 XCDs)
  const int b0 = blockIdx.x;
  const int w  = (b0 & 7) * 32 + (b0 >> 3);
  const int bx = w & 15;   // N tile
  const int by = w >> 4;   // M tile

  const unsigned short* Ag = A + (size_t)by * 256 * K_DIM;
  const unsigned short* Wg = W + (size_t)bx * 256 * K_DIM;

  // stage addressing (per-thread, constant across tiles)
  const int srow0  = tid >> 3;                    // row 0..63 (q=0); +64 for q=1
  const int schunk = (tid & 7) ^ (srow0 & 7);     // inverse-swizzled source chunk
  // read addressing: swizzled k-offset within a 64-elem row
  const int ks0 = (((lane >> 4) * 8)) ^ ((lane & 7) << 3);
  const int ks1 = ks0 ^ 32;

  f32x4 acc[2][2][4][2];
#pragma unroll
  for (int a = 0; a < 2; ++a)
#pragma unroll
    for (int b = 0; b < 2; ++b)
#pragma unroll
      for (int m = 0; m < 4; ++m)
#pragma unroll
        for (int n = 0; n < 2; ++n) acc[a][b][m][n] = (f32x4){0.f, 0.f, 0.f, 0.f};

  // prologue: tile0 all 4 halves, tile1 A-h0/B-h0
  STAGE(&lds[0][0][0][0], Ag, 0);
  STAGE(&lds[0][1][0][0], Wg, 0);
  STAGE(&lds[0][0][1][0], Ag + 128 * K_DIM, 0);
  STAGE(&lds[0][1][1][0], Wg + 128 * K_DIM, 0);
  STAGE(&lds[1][0][0][0], Ag, 64);
  STAGE(&lds[1][1][0][0], Wg, 64);
  asm volatile("s_waitcnt vmcnt(4)" ::: "memory");
  bar();

  for (int t2 = 0; t2 < NT; t2 += 2) {
    {  // tile t2, slot 0
      const int t = t2;
      const int k1 = (t + 1) * 64, k2 = (t + 2) * 64;
      PHASE(0, 0, 0, if (t < NT - 1) STAGE(&lds[1][0][1][0], Ag + 128 * K_DIM, k1), );
      PHASE(0, 0, 1, if (t < NT - 1) STAGE(&lds[1][1][1][0], Wg + 128 * K_DIM, k1), );
      PHASE(0, 1, 0, if (t < NT - 2) STAGE(&lds[0][0][0][0], Ag, k2), );
      PHASE(0, 1, 1, if (t < NT - 2) STAGE(&lds[0][1][0][0], Wg, k2),
            asm volatile("s_waitcnt vmcnt(4)" ::: "memory"));
    }
    {  // tile t2+1, slot 1
      const int t = t2 + 1;
      const int k1 = (t + 1) * 64, k2 = (t + 2) * 64;
      PHASE(1, 0, 0, if (t < NT - 1) STAGE(&lds[0][0][1][0], Ag + 128 * K_DIM, k1), );
      PHASE(1, 0, 1, if (t < NT - 1) STAGE(&lds[0][1][1][0], Wg + 128 * K_DIM, k1), );
      PHASE(1, 1, 0, if (t < NT - 2) STAGE(&lds[1][0][0][0], Ag, k2), );
      PHASE(1, 1, 1, if (t < NT - 2) STAGE(&lds[1][1][0][0], Wg, k2),
            asm volatile("s_waitcnt vmcnt(4)" ::: "memory"));
    }
  }

  // C write: row = by*256 + mq*128 + wr*64 + m*16 + (lane>>4)*4 + r
  //          col = bx*256 + nq*128 + wc*32 + n*16 + (lane&15)
  const int rbase = by * 256 + wr * 64 + (lane >> 4) * 4;
  const int cbase = bx * 256 + wc * 32 + lrow;
#pragma unroll
  for (int mq = 0; mq < 2; ++mq)
#pragma unroll
    for (int nq = 0; nq < 2; ++nq)
#pragma unroll
      for (int m = 0; m < 4; ++m)
#pragma unroll
        for (int n = 0; n < 2; ++n) {
          const int row = rbase + mq * 128 + m * 16;
          const int col = cbase + nq * 128 + n * 16;
#pragma unroll
          for (int r = 0; r < 4; ++r)
            C[(size_t)(row + r) * N_DIM + col] = acc[mq][nq][m][n][r];
        }
}

// ---------------------------------------------------------------- epilogue
__global__ void lstm_epilogue(const float* __restrict__ gates,   // [4096][4096]
                              const float* __restrict__ c_prev,  // [4096][1024]
                              const float* __restrict__ b_i, const float* __restrict__ b_f,
                              const float* __restrict__ b_g, const float* __restrict__ b_o,
                              float* __restrict__ out) {         // [3*BH]
  int t = blockIdx.x * 256 + threadIdx.x;
  int e = t * 4;
  int b = e >> 10;
  int j = e & 1023;
  size_t rowbase = (size_t)b * N_DIM;
  f32x4 ig = *(const f32x4*)&gates[rowbase + j];
  f32x4 fg = *(const f32x4*)&gates[rowbase + 1024 + j];
  f32x4 gg = *(const f32x4*)&gates[rowbase + 2048 + j];
  f32x4 og = *(const f32x4*)&gates[rowbase + 3072 + j];
  f32x4 bi = *(const f32x4*)&b_i[j];
  f32x4 bf = *(const f32x4*)&b_f[j];
  f32x4 bg = *(const f32x4*)&b_g[j];
  f32x4 bo = *(const f32x4*)&b_o[j];
  f32x4 cp = *(const f32x4*)&c_prev[e];

  f32x4 h4, c4;
#pragma unroll
  for (int r = 0; r < 4; ++r) {
    float i_t = sigmoidf_(ig[r] + bi[r]);
    float f_t = sigmoidf_(fg[r] + bf[r]);
    float g_t = tanhf_(gg[r] + bg[r]);
    float o_t = sigmoidf_(og[r] + bo[r]);
    float c_t = f_t * cp[r] + i_t * g_t;
    c4[r] = c_t;
    h4[r] = o_t * tanhf_(c_t);
  }
  *(f32x4*)&out[e]          = h4;
  *(f32x4*)&out[BH + e]     = h4;
  *(f32x4*)&out[2 * BH + e] = c4;
}

// ---------------------------------------------------------------- launcher
extern "C" void kernel_launch(void* const* d_in, const int* in_sizes, int n_in,
                              void* d_out, int out_size, void* d_ws, size_t ws_size,
                              hipStream_t stream) {
  const float* x   = (const float*)d_in[0];
  const float* hp  = (const float*)d_in[1];
  const float* cp  = (const float*)d_in[2];
  const float* Wii = (const float*)d_in[3];
  const float* Whi = (const float*)d_in[4];
  const float* bi  = (const float*)d_in[5];
  const float* Wif = (const float*)d_in[6];
  const float* Whf = (const float*)d_in[7];
  const float* bf  = (const float*)d_in[8];
  const float* Wig = (const float*)d_in[9];
  const float* Whg = (const float*)d_in[10];
  const float* bg  = (const float*)d_in[11];
  const float* Wio = (const float*)d_in[12];
  const float* Who = (const float*)d_in[13];
  const float* bo  = (const float*)d_in[14];

  unsigned short* Abf   = (unsigned short*)d_ws;                        // 16 MiB
  unsigned short* Wbf   = (unsigned short*)((char*)d_ws + (16u << 20)); // 16 MiB
  float*          gates = (float*)((char*)d_ws + (32u << 20));          // 64 MiB
  float*          out   = (float*)d_out;

  pack_a<<<8192, 256, 0, stream>>>(x, hp, Abf);
  pack_w<<<8192, 256, 0, stream>>>(Wii, Wif, Wig, Wio, Whi, Whf, Whg, Who, Wbf);
  gemm_gates<<<256, 512, 0, stream>>>(Abf, Wbf, gates);
  lstm_epilogue<<<4096, 256, 0, stream>>>(gates, cp, bi, bf, bg, bo, out);
}

// Round 4
// 214.949 us; speedup vs baseline: 1.2526x; 1.1235x over previous
//
#include <hip/hip_runtime.h>
#include <hip/hip_bf16.h>
#include <stdint.h>

#define B_DIM 4096
#define IN_DIM 1024
#define H_DIM 1024
#define K_DIM 2048   // IN + H
#define BH (B_DIM * H_DIM)
#define NT 32        // K tiles of 64

typedef __bf16 bf16x8 __attribute__((ext_vector_type(8)));
typedef float  f32x4  __attribute__((ext_vector_type(4)));

// ---------------------------------------------------------------- helpers
__device__ __forceinline__ unsigned short f2b(float f) {
  uint32_t u = __builtin_bit_cast(uint32_t, f);
  u += 0x7fffu + ((u >> 16) & 1u);
  return (unsigned short)(u >> 16);
}

__device__ __forceinline__ void load_lds16(const void* g, void* l) {
  __builtin_amdgcn_global_load_lds(
      (const __attribute__((address_space(1))) uint32_t*)g,
      (__attribute__((address_space(3))) uint32_t*)l, 16, 0, 0);
}

__device__ __forceinline__ void bar() {
  asm volatile("" ::: "memory");
  __builtin_amdgcn_s_barrier();
  asm volatile("" ::: "memory");
}

__device__ __forceinline__ float sigmoidf_(float x) {
  return 1.0f / (1.0f + __expf(-x));
}
__device__ __forceinline__ float tanhf_(float x) {
  float e = __expf(-2.0f * x);
  return (1.0f - e) / (1.0f + e);
}

// ---------------------------------------------------------------- fused pack
// A = [x | h_prev] -> bf16 [4096][2048]
// Wp: gate-interleaved bf16 [4096][2048]. Packed row R: bx=R>>8, r=R&255,
//   gate = ((r>>7)<<1) | ((r>>4)&1),  j = (bx<<6) + (((r>>5)&3)<<4) + (r&15).
//   Row R holds [W_x_gate[j] | W_h_gate[j]].
// This makes GEMM C-col fragment bits (nq,n) = gate, (wc,lrow) = unit, so the
// LSTM epilogue is lane-local in the GEMM.
__global__ void pack_all(const float* __restrict__ x, const float* __restrict__ h,
                         const float* __restrict__ Wii, const float* __restrict__ Wif,
                         const float* __restrict__ Wig, const float* __restrict__ Wio,
                         const float* __restrict__ Whi, const float* __restrict__ Whf,
                         const float* __restrict__ Whg, const float* __restrict__ Who,
                         unsigned short* __restrict__ A, unsigned short* __restrict__ Wp) {
  const int bid = blockIdx.x;
  if (bid < 8192) {                       // ---- A part
    int t = bid * 256 + threadIdx.x;
    int e = t * 4;
    int b = e >> 11;
    int k = e & 2047;
    const float* src = (k < IN_DIM) ? (x + (size_t)b * IN_DIM + k)
                                    : (h + (size_t)b * H_DIM + (k - IN_DIM));
    f32x4 v = *(const f32x4*)src;
    ushort4 o;
    o.x = f2b(v[0]); o.y = f2b(v[1]); o.z = f2b(v[2]); o.w = f2b(v[3]);
    *(ushort4*)(A + (size_t)b * K_DIM + k) = o;
  } else {                                // ---- W part
    int t = (bid - 8192) * 256 + threadIdx.x;
    int e = t * 4;
    int n = e >> 11;                      // packed row (block-uniform: 1024 elems = half row)
    int k = e & 2047;
    int r = n & 255;
    int gate = ((r >> 7) << 1) | ((r >> 4) & 1);
    int j = ((n >> 8) << 6) + (((r >> 5) & 3) << 4) + (r & 15);
    const float* Wx = (gate == 0) ? Wii : (gate == 1) ? Wif : (gate == 2) ? Wig : Wio;
    const float* Wh = (gate == 0) ? Whi : (gate == 1) ? Whf : (gate == 2) ? Whg : Who;
    const float* src = (k < IN_DIM) ? (Wx + (size_t)j * IN_DIM + k)
                                    : (Wh + (size_t)j * H_DIM + (k - IN_DIM));
    f32x4 v = *(const f32x4*)src;
    ushort4 o;
    o.x = f2b(v[0]); o.y = f2b(v[1]); o.z = f2b(v[2]); o.w = f2b(v[3]);
    *(ushort4*)(Wp + (size_t)n * K_DIM + k) = o;
  }
}

// ---------------------------------------------------------------- fused GEMM + LSTM epilogue
// virtual C[b][col] = sum_k A[b][k]*Wp[col(block-tile)][k]; epilogue lane-local.
//
// LDS: [slot][A=0/B=1][half][128 x 64] bf16, 128 KiB.
// Stage: linear LDS dest, inverse-swizzled global source chunk.
// Read: ds_read_b128, k-offset ^ ((row&7)<<3) elems  (T2; conflicts = 0 measured).
// Schedule per tile t (slot s), quadrant phases (mq,nq)=(00),(01),(10),(11):
//   ph1: stage Bh1(t+1)->s^1 | ph2: stage Ah1(t+1)->s^1
//   ph3: stage Ah0(t+2)->s   | ph4: stage Bh0(t+2)->s
// Reads: ph1 {Ah0,Bh0}, ph2 {Ah0,Bh1}, ph3 {Ah1,Bh0}, ph4 {Ah1,Bh1}.
// Waits (derived queue trace, every waited load has >=4 phases lead):
//   vmcnt(8) at end of ph1, ph2, ph4; none at ph3.
// Tail (last 2 tiles): vmcnt 8,8,-,4 then 2,0,-,-.

#define VM8 asm volatile("s_waitcnt vmcnt(8)" ::: "memory")
#define VM4 asm volatile("s_waitcnt vmcnt(4)" ::: "memory")
#define VM2 asm volatile("s_waitcnt vmcnt(2)" ::: "memory")
#define VM0 asm volatile("s_waitcnt vmcnt(0)" ::: "memory")

#define STAGE(ldsbase, gbase, kelem) do {                                        \
  const unsigned short* g0_ = (gbase) + (size_t)srow0 * K_DIM + (kelem) + schunk * 8; \
  load_lds16(g0_, (ldsbase) + tid * 8);                                          \
  load_lds16(g0_ + (size_t)64 * K_DIM, (ldsbase) + 4096 + tid * 8);              \
} while (0)

#define PHASE(SLOT, MQ, NQ, STAGE_STMT, VM_WAIT) do {                            \
  const unsigned short* As_ = &lds[SLOT][0][MQ][0];                              \
  const unsigned short* Bs_ = &lds[SLOT][1][NQ][0];                              \
  bf16x8 af[4][2], bq[2][2];                                                     \
  _Pragma("unroll")                                                              \
  for (int m = 0; m < 4; ++m) {                                                  \
    int ro = (wr * 64 + m * 16 + lrow) * 64;                                     \
    af[m][0] = *(const bf16x8*)(As_ + ro + ks0);                                 \
    af[m][1] = *(const bf16x8*)(As_ + ro + ks1);                                 \
  }                                                                              \
  _Pragma("unroll")                                                              \
  for (int n = 0; n < 2; ++n) {                                                  \
    int ro = (wc * 32 + n * 16 + lrow) * 64;                                     \
    bq[n][0] = *(const bf16x8*)(Bs_ + ro + ks0);                                 \
    bq[n][1] = *(const bf16x8*)(Bs_ + ro + ks1);                                 \
  }                                                                              \
  STAGE_STMT;                                                                    \
  bar();                                                                         \
  asm volatile("s_waitcnt lgkmcnt(0)" ::: "memory");                             \
  __builtin_amdgcn_sched_barrier(0);                                             \
  __builtin_amdgcn_s_setprio(1);                                                 \
  _Pragma("unroll")                                                              \
  for (int m = 0; m < 4; ++m)                                                    \
    _Pragma("unroll")                                                            \
    for (int n = 0; n < 2; ++n) {                                                \
      acc[MQ][NQ][m][n] = __builtin_amdgcn_mfma_f32_16x16x32_bf16(               \
          af[m][0], bq[n][0], acc[MQ][NQ][m][n], 0, 0, 0);                       \
      acc[MQ][NQ][m][n] = __builtin_amdgcn_mfma_f32_16x16x32_bf16(               \
          af[m][1], bq[n][1], acc[MQ][NQ][m][n], 0, 0, 0);                       \
    }                                                                            \
  __builtin_amdgcn_s_setprio(0);                                                 \
  __builtin_amdgcn_sched_barrier(0);                                             \
  VM_WAIT;                                                                       \
  bar();                                                                         \
} while (0)

__global__ __launch_bounds__(512, 2) void gemm_lstm(
    const unsigned short* __restrict__ A,    // bf16 [4096][2048]
    const unsigned short* __restrict__ Wp,   // bf16 [4096][2048] gate-interleaved
    const float* __restrict__ c_prev,        // [4096][1024]
    const float* __restrict__ b_i, const float* __restrict__ b_f,
    const float* __restrict__ b_g, const float* __restrict__ b_o,
    float* __restrict__ out) {               // [3*BH] = h, h, c
  __shared__ unsigned short lds[2][2][2][128 * 64];   // 128 KiB

  const int tid  = threadIdx.x;
  const int lane = tid & 63;
  const int wid  = tid >> 6;
  const int wr   = wid >> 2;     // 0..1
  const int wc   = wid & 3;      // 0..3
  const int lrow = lane & 15;

  // T1: bijective XCD swizzle (256 blocks, 8 XCDs)
  const int b0 = blockIdx.x;
  const int w  = (b0 & 7) * 32 + (b0 >> 3);
  const int bx = w & 15;   // N tile (64 hidden units, all 4 gates)
  const int by = w >> 4;   // M tile (256 batch rows)

  const unsigned short* Ag = A  + (size_t)by * 256 * K_DIM;
  const unsigned short* Wg = Wp + (size_t)bx * 256 * K_DIM;

  const int srow0  = tid >> 3;
  const int schunk = (tid & 7) ^ (srow0 & 7);
  const int ks0 = ((lane >> 4) * 8) ^ ((lane & 7) << 3);
  const int ks1 = ks0 ^ 32;

  f32x4 acc[2][2][4][2];
#pragma unroll
  for (int a = 0; a < 2; ++a)
#pragma unroll
    for (int b = 0; b < 2; ++b)
#pragma unroll
      for (int m = 0; m < 4; ++m)
#pragma unroll
        for (int n = 0; n < 2; ++n) acc[a][b][m][n] = (f32x4){0.f, 0.f, 0.f, 0.f};

  // prologue: tile0 {Ah0,Bh0,Ah1,Bh1}, tile1 {Ah0,Bh0}; land tile0 fully.
  STAGE(&lds[0][0][0][0], Ag, 0);
  STAGE(&lds[0][1][0][0], Wg, 0);
  STAGE(&lds[0][0][1][0], Ag + 128 * K_DIM, 0);
  STAGE(&lds[0][1][1][0], Wg + 128 * K_DIM, 0);
  STAGE(&lds[1][0][0][0], Ag, 64);
  STAGE(&lds[1][1][0][0], Wg, 64);
  VM4;
  bar();

  for (int t2 = 0; t2 < NT - 2; t2 += 2) {
    {  // tile t2, slot 0
      const int k1 = (t2 + 1) * 64, k2 = (t2 + 2) * 64;
      PHASE(0, 0, 0, STAGE(&lds[1][1][1][0], Wg + 128 * K_DIM, k1), VM8);
      PHASE(0, 0, 1, STAGE(&lds[1][0][1][0], Ag + 128 * K_DIM, k1), VM8);
      PHASE(0, 1, 0, STAGE(&lds[0][0][0][0], Ag, k2), );
      PHASE(0, 1, 1, STAGE(&lds[0][1][0][0], Wg, k2), VM8);
    }
    {  // tile t2+1, slot 1
      const int k1 = (t2 + 2) * 64, k2 = (t2 + 3) * 64;
      PHASE(1, 0, 0, STAGE(&lds[0][1][1][0], Wg + 128 * K_DIM, k1), VM8);
      PHASE(1, 0, 1, STAGE(&lds[0][0][1][0], Ag + 128 * K_DIM, k1), VM8);
      PHASE(1, 1, 0, STAGE(&lds[1][0][0][0], Ag, k2), );
      PHASE(1, 1, 1, STAGE(&lds[1][1][0][0], Wg, k2), VM8);
    }
  }
  {  // tail: tile NT-2 (slot 0) — stage only Bh1/Ah1 of NT-1
    const int k1 = (NT - 1) * 64;
    PHASE(0, 0, 0, STAGE(&lds[1][1][1][0], Wg + 128 * K_DIM, k1), VM8);
    PHASE(0, 0, 1, STAGE(&lds[1][0][1][0], Ag + 128 * K_DIM, k1), VM8);
    PHASE(0, 1, 0, , );
    PHASE(0, 1, 1, , VM4);
    // tile NT-1 (slot 1) — nothing left to stage
    PHASE(1, 0, 0, , VM2);
    PHASE(1, 0, 1, , VM0);
    PHASE(1, 1, 0, , );
    PHASE(1, 1, 1, , );
  }

  // ---- fused LSTM epilogue (lane-local: gate = (nq,n), unit = (wc,lrow)) ----
  const int j  = bx * 64 + wc * 16 + lrow;          // global hidden unit
  const float biv = b_i[j], bfv = b_f[j], bgv = b_g[j], bov = b_o[j];
  const int rb = by * 256 + wr * 64 + (lane >> 4) * 4;
#pragma unroll
  for (int mq = 0; mq < 2; ++mq)
#pragma unroll
    for (int m = 0; m < 4; ++m)
#pragma unroll
      for (int r = 0; r < 4; ++r) {
        const int row = rb + mq * 128 + m * 16 + r;
        const float iv = sigmoidf_(acc[mq][0][m][0][r] + biv);
        const float fv = sigmoidf_(acc[mq][0][m][1][r] + bfv);
        const float gv = tanhf_(acc[mq][1][m][0][r] + bgv);
        const float ov = sigmoidf_(acc[mq][1][m][1][r] + bov);
        const size_t idx = (size_t)row * H_DIM + j;
        const float cv = fv * c_prev[idx] + iv * gv;
        const float hv = ov * tanhf_(cv);
        out[idx]          = hv;
        out[BH + idx]     = hv;
        out[2 * BH + idx] = cv;
      }
}

// ---------------------------------------------------------------- launcher
extern "C" void kernel_launch(void* const* d_in, const int* in_sizes, int n_in,
                              void* d_out, int out_size, void* d_ws, size_t ws_size,
                              hipStream_t stream) {
  const float* x   = (const float*)d_in[0];
  const float* hp  = (const float*)d_in[1];
  const float* cp  = (const float*)d_in[2];
  const float* Wii = (const float*)d_in[3];
  const float* Whi = (const float*)d_in[4];
  const float* bi  = (const float*)d_in[5];
  const float* Wif = (const float*)d_in[6];
  const float* Whf = (const float*)d_in[7];
  const float* bf  = (const float*)d_in[8];
  const float* Wig = (const float*)d_in[9];
  const float* Whg = (const float*)d_in[10];
  const float* bg  = (const float*)d_in[11];
  const float* Wio = (const float*)d_in[12];
  const float* Who = (const float*)d_in[13];
  const float* bo  = (const float*)d_in[14];

  unsigned short* Abf = (unsigned short*)d_ws;                        // 16 MiB
  unsigned short* Wbf = (unsigned short*)((char*)d_ws + (16u << 20)); // 16 MiB
  float*          out = (float*)d_out;

  pack_all<<<16384, 256, 0, stream>>>(x, hp, Wii, Wif, Wig, Wio,
                                      Whi, Whf, Whg, Who, Abf, Wbf);
  gemm_lstm<<<256, 512, 0, stream>>>(Abf, Wbf, cp, bi, bf, bg, bo, out);
}

// Round 6
// 210.640 us; speedup vs baseline: 1.2782x; 1.0205x over previous
//
#include <hip/hip_runtime.h>
#include <hip/hip_bf16.h>
#include <stdint.h>

#define B_DIM 4096
#define IN_DIM 1024
#define H_DIM 1024
#define K_DIM 2048   // IN + H
#define BH (B_DIM * H_DIM)
#define NT 32        // K tiles of 64

typedef __bf16 bf16x8 __attribute__((ext_vector_type(8)));
typedef float  f32x4  __attribute__((ext_vector_type(4)));

// ---------------------------------------------------------------- helpers
__device__ __forceinline__ unsigned short f2b(float f) {
  uint32_t u = __builtin_bit_cast(uint32_t, f);
  u += 0x7fffu + ((u >> 16) & 1u);
  return (unsigned short)(u >> 16);
}

__device__ __forceinline__ void load_lds16(const void* g, void* l) {
  __builtin_amdgcn_global_load_lds(
      (const __attribute__((address_space(1))) uint32_t*)g,
      (__attribute__((address_space(3))) uint32_t*)l, 16, 0, 0);
}

__device__ __forceinline__ void bar() {
  asm volatile("" ::: "memory");
  __builtin_amdgcn_s_barrier();
  asm volatile("" ::: "memory");
}

__device__ __forceinline__ float sigmoidf_(float x) {
  return 1.0f / (1.0f + __expf(-x));
}
__device__ __forceinline__ float tanhf_(float x) {
  float e = __expf(-2.0f * x);
  return (1.0f - e) / (1.0f + e);
}

// ---------------------------------------------------------------- fused pack
// A = [x | h_prev] -> bf16 [4096][2048]
// Wp: gate-interleaved bf16 [4096][2048]. Packed row R: bx=R>>8, r=R&255,
//   gate = ((r>>7)<<1) | ((r>>4)&1),  j = (bx<<6) + (((r>>5)&3)<<4) + (r&15).
__global__ void pack_all(const float* __restrict__ x, const float* __restrict__ h,
                         const float* __restrict__ Wii, const float* __restrict__ Wif,
                         const float* __restrict__ Wig, const float* __restrict__ Wio,
                         const float* __restrict__ Whi, const float* __restrict__ Whf,
                         const float* __restrict__ Whg, const float* __restrict__ Who,
                         unsigned short* __restrict__ A, unsigned short* __restrict__ Wp) {
  const int bid = blockIdx.x;
  if (bid < 8192) {                       // ---- A part
    int t = bid * 256 + threadIdx.x;
    int e = t * 4;
    int b = e >> 11;
    int k = e & 2047;
    const float* src = (k < IN_DIM) ? (x + (size_t)b * IN_DIM + k)
                                    : (h + (size_t)b * H_DIM + (k - IN_DIM));
    f32x4 v = *(const f32x4*)src;
    ushort4 o;
    o.x = f2b(v[0]); o.y = f2b(v[1]); o.z = f2b(v[2]); o.w = f2b(v[3]);
    *(ushort4*)(A + (size_t)b * K_DIM + k) = o;
  } else {                                // ---- W part
    int t = (bid - 8192) * 256 + threadIdx.x;
    int e = t * 4;
    int n = e >> 11;
    int k = e & 2047;
    int r = n & 255;
    int gate = ((r >> 7) << 1) | ((r >> 4) & 1);
    int j = ((n >> 8) << 6) + (((r >> 5) & 3) << 4) + (r & 15);
    const float* Wx = (gate == 0) ? Wii : (gate == 1) ? Wif : (gate == 2) ? Wig : Wio;
    const float* Wh = (gate == 0) ? Whi : (gate == 1) ? Whf : (gate == 2) ? Whg : Who;
    const float* src = (k < IN_DIM) ? (Wx + (size_t)j * IN_DIM + k)
                                    : (Wh + (size_t)j * H_DIM + (k - IN_DIM));
    f32x4 v = *(const f32x4*)src;
    ushort4 o;
    o.x = f2b(v[0]); o.y = f2b(v[1]); o.z = f2b(v[2]); o.w = f2b(v[3]);
    *(ushort4*)(Wp + (size_t)n * K_DIM + k) = o;
  }
}

// ---------------------------------------------------------------- fused GEMM + LSTM
// Phase order per tile: (00)->(01)->(11)->(10); A-quad held in regs across its
// 2 phases, BOTH B-quads resident. LDS reads/tile/wave: 8+4+8+0 = 24 (minimum)
// vs 48 in the quadrant-re-read version. B0 of tile t+1 is ds_read at ph4(t)
// after the vm-wait (ph4 has no other LDS reads).
//
// Stage stream (tile t, slot s=t&1):
//   ph1: Bh0(t+1)->s^1   ph2: Ah0(t+2)->s   ph3: Bh1(t+2)->s   ph4: Ah1(t+2)->s
// Buffer free-times (reads-complete barrier): Ah0(s): end ph1(t); Bh1(s): end
// ph2(t); Ah1(s): end ph3(t); Bh0(s^1): read at ph4(t-1), free after the
// barrier that ends ph4(t-1). Each stage targets a buffer freed >=1 barrier
// earlier. ✓
// Wait ledger (loads, 2/stage): prologue 14 loads (tile0 = L1-8, Ah0/Bh1/Ah1
// of tile1 = L9-14), VM6 -> tile0 landed. Steady: VM6 at ph4(t) leaves only
// STG2-4(t) outstanding -> everything through Bh0(t+1) landed -> tile t+1
// complete, 3-7 phase lead per load. Tail: VM0 at ph4(30).

#define VM6 asm volatile("s_waitcnt vmcnt(6)" ::: "memory")
#define VM0 asm volatile("s_waitcnt vmcnt(0)" ::: "memory")

#define STAGE(ldsbase, gbase, kelem) do {                                        \
  const unsigned short* g0_ = (gbase) + (size_t)srow0 * K_DIM + (kelem) + schunk * 8; \
  load_lds16(g0_, (ldsbase) + tid * 8);                                          \
  load_lds16(g0_ + (size_t)64 * K_DIM, (ldsbase) + 4096 + tid * 8);              \
} while (0)

#define RA(S, MQ) do {                                                           \
  _Pragma("unroll")                                                              \
  for (int m = 0; m < 4; ++m) {                                                  \
    const unsigned short* p_ = &lds[S][0][MQ][(wr * 64 + m * 16 + lrow) * 64];   \
    af[m][0] = *(const bf16x8*)(p_ + ks0);                                       \
    af[m][1] = *(const bf16x8*)(p_ + ks1);                                       \
  }                                                                              \
} while (0)

#define RB(S, NQ) do {                                                           \
  _Pragma("unroll")                                                              \
  for (int n = 0; n < 2; ++n) {                                                  \
    const unsigned short* p_ = &lds[S][1][NQ][(wc * 32 + n * 16 + lrow) * 64];   \
    bq[NQ][n][0] = *(const bf16x8*)(p_ + ks0);                                   \
    bq[NQ][n][1] = *(const bf16x8*)(p_ + ks1);                                   \
  }                                                                              \
} while (0)

#define SYNC do { bar();                                                         \
  asm volatile("s_waitcnt lgkmcnt(0)" ::: "memory");                             \
  __builtin_amdgcn_sched_barrier(0); } while (0)

#define EPH do { __builtin_amdgcn_sched_barrier(0); bar(); } while (0)

#define MM(MQ, NQ) do {                                                          \
  __builtin_amdgcn_s_setprio(1);                                                 \
  _Pragma("unroll")                                                              \
  for (int m = 0; m < 4; ++m)                                                    \
    _Pragma("unroll")                                                            \
    for (int n = 0; n < 2; ++n) {                                                \
      acc[MQ][NQ][m][n] = __builtin_amdgcn_mfma_f32_16x16x32_bf16(               \
          af[m][0], bq[NQ][n][0], acc[MQ][NQ][m][n], 0, 0, 0);                   \
      acc[MQ][NQ][m][n] = __builtin_amdgcn_mfma_f32_16x16x32_bf16(               \
          af[m][1], bq[NQ][n][1], acc[MQ][NQ][m][n], 0, 0, 0);                   \
    }                                                                            \
  __builtin_amdgcn_s_setprio(0);                                                 \
} while (0)

// 4 phases of one K-tile. STG* issue before the first barrier of their phase;
// VMW+NEXTB sit after ph4's MFMA, before the tile-ending barrier.
#define TILE(S, STG1, STG2, STG3, STG4, VMW, NEXTB) do {                         \
  RA(S, 0); STG1; SYNC; MM(0, 0); EPH;                                           \
  RB(S, 1); STG2; SYNC; MM(0, 1); EPH;                                           \
  RA(S, 1); STG3; SYNC; MM(1, 1); EPH;                                           \
  STG4;     SYNC; MM(1, 0); VMW; NEXTB; EPH;                                     \
} while (0)

__global__ __launch_bounds__(512, 2) void gemm_lstm(
    const unsigned short* __restrict__ A,    // bf16 [4096][2048]
    const unsigned short* __restrict__ Wp,   // bf16 [4096][2048] gate-interleaved
    const float* __restrict__ c_prev,        // [4096][1024]
    const float* __restrict__ b_i, const float* __restrict__ b_f,
    const float* __restrict__ b_g, const float* __restrict__ b_o,
    float* __restrict__ out) {               // [3*BH] = h, h, c
  __shared__ unsigned short lds[2][2][2][128 * 64];   // 128 KiB

  const int tid  = threadIdx.x;
  const int lane = tid & 63;
  const int wid  = tid >> 6;
  const int wr   = wid >> 2;     // 0..1
  const int wc   = wid & 3;      // 0..3
  const int lrow = lane & 15;

  // T1: bijective XCD swizzle (256 blocks, 8 XCDs)
  const int b0 = blockIdx.x;
  const int w  = (b0 & 7) * 32 + (b0 >> 3);
  const int bx = w & 15;   // N tile (64 hidden units x 4 gates)
  const int by = w >> 4;   // M tile (256 batch rows)

  const unsigned short* Ag = A  + (size_t)by * 256 * K_DIM;
  const unsigned short* Wg = Wp + (size_t)bx * 256 * K_DIM;

  const int srow0  = tid >> 3;
  const int schunk = (tid & 7) ^ (srow0 & 7);
  const int ks0 = ((lane >> 4) * 8) ^ ((lane & 7) << 3);
  const int ks1 = ks0 ^ 32;

  bf16x8 af[4][2];        // current A-quad fragments (held 2 phases)
  bf16x8 bq[2][2][2];     // BOTH B-quads resident [nq][n][kslice]

  f32x4 acc[2][2][4][2];
#pragma unroll
  for (int a = 0; a < 2; ++a)
#pragma unroll
    for (int b = 0; b < 2; ++b)
#pragma unroll
      for (int m = 0; m < 4; ++m)
#pragma unroll
        for (int n = 0; n < 2; ++n) acc[a][b][m][n] = (f32x4){0.f, 0.f, 0.f, 0.f};

  // prologue: tile0 {Ah0,Bh0,Bh1,Ah1} = L1-8; tile1 {Ah0,Bh1,Ah1} = L9-14.
  STAGE(&lds[0][0][0][0], Ag, 0);                  // Ah0(0)
  STAGE(&lds[0][1][0][0], Wg, 0);                  // Bh0(0)
  STAGE(&lds[0][1][1][0], Wg + 128 * K_DIM, 0);    // Bh1(0)
  STAGE(&lds[0][0][1][0], Ag + 128 * K_DIM, 0);    // Ah1(0)
  STAGE(&lds[1][0][0][0], Ag, 64);                 // Ah0(1)
  STAGE(&lds[1][1][1][0], Wg + 128 * K_DIM, 64);   // Bh1(1)
  STAGE(&lds[1][0][1][0], Ag + 128 * K_DIM, 64);   // Ah1(1)
  VM6;            // tile0 (L1-8) landed
  bar();
  RB(0, 0);       // bq[0] for tile0 (lgkm waited at ph1's SYNC)

  for (int t2 = 0; t2 < 30; t2 += 2) {
    const int kA = (t2 + 1) * 64;
    const int kB = (t2 + 2) * 64;
    const int kC = (t2 + 3) * 64;
    TILE(0,
         STAGE(&lds[1][1][0][0], Wg, kA),                  // Bh0(t+1) -> s1
         STAGE(&lds[0][0][0][0], Ag, kB),                  // Ah0(t+2) -> s0
         STAGE(&lds[0][1][1][0], Wg + 128 * K_DIM, kB),    // Bh1(t+2) -> s0
         STAGE(&lds[0][0][1][0], Ag + 128 * K_DIM, kB),    // Ah1(t+2) -> s0
         VM6, RB(1, 0));
    TILE(1,
         STAGE(&lds[0][1][0][0], Wg, kB),                  // Bh0(t+2) -> s0
         STAGE(&lds[1][0][0][0], Ag, kC),                  // Ah0(t+3) -> s1
         STAGE(&lds[1][1][1][0], Wg + 128 * K_DIM, kC),    // Bh1(t+3) -> s1
         STAGE(&lds[1][0][1][0], Ag + 128 * K_DIM, kC),    // Ah1(t+3) -> s1
         VM6, RB(0, 0));
  }
  // tile 30 (slot 0): only Bh0(31) left to stage; then land everything.
  TILE(0, STAGE(&lds[1][1][0][0], Wg, 31 * 64), , , , VM0, RB(1, 0));
  // tile 31 (slot 1): nothing to stage or wait.
  TILE(1, , , , , , );

  // ---- fused LSTM epilogue (lane-local: gate = (nq,n), unit = (wc,lrow)) ----
  const int j  = bx * 64 + wc * 16 + lrow;          // global hidden unit
  const float biv = b_i[j], bfv = b_f[j], bgv = b_g[j], bov = b_o[j];
  const int rb = by * 256 + wr * 64 + (lane >> 4) * 4;
#pragma unroll
  for (int mq = 0; mq < 2; ++mq)
#pragma unroll
    for (int m = 0; m < 4; ++m)
#pragma unroll
      for (int r = 0; r < 4; ++r) {
        const int row = rb + mq * 128 + m * 16 + r;
        const float iv = sigmoidf_(acc[mq][0][m][0][r] + biv);
        const float fv = sigmoidf_(acc[mq][0][m][1][r] + bfv);
        const float gv = tanhf_(acc[mq][1][m][0][r] + bgv);
        const float ov = sigmoidf_(acc[mq][1][m][1][r] + bov);
        const size_t idx = (size_t)row * H_DIM + j;
        const float cv = fv * c_prev[idx] + iv * gv;
        const float hv = ov * tanhf_(cv);
        out[idx]          = hv;
        out[BH + idx]     = hv;
        out[2 * BH + idx] = cv;
      }
}

// ---------------------------------------------------------------- launcher
extern "C" void kernel_launch(void* const* d_in, const int* in_sizes, int n_in,
                              void* d_out, int out_size, void* d_ws, size_t ws_size,
                              hipStream_t stream) {
  const float* x   = (const float*)d_in[0];
  const float* hp  = (const float*)d_in[1];
  const float* cp  = (const float*)d_in[2];
  const float* Wii = (const float*)d_in[3];
  const float* Whi = (const float*)d_in[4];
  const float* bi  = (const float*)d_in[5];
  const float* Wif = (const float*)d_in[6];
  const float* Whf = (const float*)d_in[7];
  const float* bf  = (const float*)d_in[8];
  const float* Wig = (const float*)d_in[9];
  const float* Whg = (const float*)d_in[10];
  const float* bg  = (const float*)d_in[11];
  const float* Wio = (const float*)d_in[12];
  const float* Who = (const float*)d_in[13];
  const float* bo  = (const float*)d_in[14];

  unsigned short* Abf = (unsigned short*)d_ws;                        // 16 MiB
  unsigned short* Wbf = (unsigned short*)((char*)d_ws + (16u << 20)); // 16 MiB
  float*          out = (float*)d_out;

  pack_all<<<16384, 256, 0, stream>>>(x, hp, Wii, Wif, Wig, Wio,
                                      Whi, Whf, Whg, Who, Abf, Wbf);
  gemm_lstm<<<256, 512, 0, stream>>>(Abf, Wbf, cp, bi, bf, bg, bo, out);
}